// Round 2
// baseline (297.278 us; speedup 1.0000x reference)
//
#include <hip/hip_runtime.h>

#define N_NODES 50000
#define NPB 128                    // nodes per bucket
#define NBUCKET ((N_NODES + NPB - 1) / NPB)   // 391
#define CAP 2816                   // edges per bucket region (mean 2048 + 17 sigma)
#define CHUNK 4096                 // edges per partition block

// ---------------- init: per-bucket global cursors ----------------

__global__ void k_init(int* __restrict__ gcursor) {
    int b = threadIdx.x;
    if (b < NBUCKET) gcursor[b] = b * CAP;
}

// ---------------- partition: LDS counting-sort per chunk, coalesced run writes ----
// edge word: src(16b) | ldst(7b)<<16 | bucket(9b)<<23

__global__ __launch_bounds__(512) void k_part(const int* __restrict__ src,
                                              const int* __restrict__ dst,
                                              int* __restrict__ gcursor,
                                              int* __restrict__ ewords, int E) {
    __shared__ int words[CHUNK];   // 16 KB
    __shared__ int hist[512];      // hist, then cursor
    __shared__ int lstart[512];
    __shared__ int gbase[512];

    int tid = threadIdx.x;
    int cbase = blockIdx.x * CHUNK;
    int count = min(CHUNK, E - cbase);

    hist[tid] = 0;
    __syncthreads();

    // phase 1: read edges, histogram buckets, keep packed words in regs
    int w[CHUNK / 512];
#pragma unroll
    for (int r = 0; r < CHUNK / 512; r++) {
        int i = cbase + tid + 512 * r;
        if (i < E) {
            int s = src[i];
            int d = dst[i];
            int b = d >> 7;
            w[r] = s | ((d & 127) << 16) | (b << 23);
            atomicAdd(&hist[b], 1);
        } else {
            w[r] = -1;
        }
    }
    __syncthreads();

    // phase 2: exclusive scan of hist[512]
    int h = hist[tid];
    for (int off = 1; off < 512; off <<= 1) {
        int t = (tid >= off) ? hist[tid - off] : 0;
        __syncthreads();
        hist[tid] += t;
        __syncthreads();
    }
    int excl = hist[tid] - h;
    __syncthreads();
    hist[tid] = excl;      // becomes local cursor
    lstart[tid] = excl;
    __syncthreads();

    // phase 3: scatter words into LDS grouped by bucket
#pragma unroll
    for (int r = 0; r < CHUNK / 512; r++) {
        if (w[r] != -1) {
            int b = ((unsigned)w[r]) >> 23;
            int pos = atomicAdd(&hist[b], 1);
            words[pos] = w[r];
        }
    }
    __syncthreads();

    // phase 4: one global cursor bump per bucket per chunk
    if (tid < NBUCKET) {
        int nb = hist[tid] - lstart[tid];
        gbase[tid] = (nb > 0) ? atomicAdd(&gcursor[tid], nb) : 0;
    }
    __syncthreads();

    // phase 5: coalesced run write-out
    for (int i = tid; i < count; i += 512) {
        int ww = words[i];
        int b = ((unsigned)ww) >> 23;
        int g = gbase[b] + (i - lstart[b]);   // absolute (gcursor init = b*CAP)
        ewords[g] = ww;
    }
}

// ---------------- degrees: per-bucket LDS count -> dinv ----------------

__global__ __launch_bounds__(256) void k_deg(const int* __restrict__ ewords,
                                             const int* __restrict__ gcursor,
                                             float* __restrict__ dinv) {
    __shared__ int cnt[NPB];
    int tid = threadIdx.x;
    int b = blockIdx.x;
    if (tid < NPB) cnt[tid] = 0;
    __syncthreads();

    int base = b * CAP;
    int count = gcursor[b] - base;
    for (int i = tid; i < count; i += 256) {
        int ldst = (ewords[base + i] >> 16) & 127;
        atomicAdd(&cnt[ldst], 1);
    }
    __syncthreads();

    if (tid < NPB) {
        int node = b * NPB + tid;
        if (node < N_NODES) dinv[node] = rsqrtf((float)(cnt[tid] + 1));
    }
}

// ---------------- GEMM 1: h1s[n][j] = dinv[n] * sum_k x[n][k] * W1[k][j] ----------

__global__ __launch_bounds__(256) void k_gemm1(const float* __restrict__ x,
                                               const float* __restrict__ W1,
                                               const float* __restrict__ dinv,
                                               float* __restrict__ h1s) {
    __shared__ float sx[16 * 132];
    __shared__ float swT[16 * 132];
    int tid = threadIdx.x;
    int n0 = blockIdx.x * 16;

#pragma unroll
    for (int r = 0; r < 2; r++) {
        int q = tid + 256 * r;
        float4 v = ((const float4*)W1)[q];
        int k = q >> 2;
        int j4 = (q & 3) << 2;
        swT[(j4 + 0) * 132 + k] = v.x;
        swT[(j4 + 1) * 132 + k] = v.y;
        swT[(j4 + 2) * 132 + k] = v.z;
        swT[(j4 + 3) * 132 + k] = v.w;
    }
    const float4* x4 = (const float4*)(x + (size_t)n0 * 128);
#pragma unroll
    for (int r = 0; r < 2; r++) {
        int q = tid + 256 * r;
        float4 v = x4[q];
        int node = q >> 5;
        int k = (q & 31) << 2;
        *(float4*)&sx[node * 132 + k] = v;
    }
    __syncthreads();

    int node = tid >> 4;
    int j = tid & 15;
    float acc = 0.f;
#pragma unroll
    for (int k = 0; k < 128; k += 4) {
        float4 a = *(const float4*)&sx[node * 132 + k];
        float4 bb = *(const float4*)&swT[j * 132 + k];
        acc = fmaf(a.x, bb.x, acc);
        acc = fmaf(a.y, bb.y, acc);
        acc = fmaf(a.z, bb.z, acc);
        acc = fmaf(a.w, bb.w, acc);
    }
    int n = n0 + node;
    h1s[(size_t)n * 16 + j] = dinv[n] * acc;
}

// ---------------- aggregation: one block per bucket, LDS float accumulators ------
// mode 0: out = dinv * relu(dinv*(sum + self) + bias)   (hin = h1s, pre-scaled)
// mode 1: out = dinv * (sum + self)                     (hin = z1s, pre-scaled)

__global__ __launch_bounds__(512) void k_agg(const float* __restrict__ hin,
                                             const int* __restrict__ ewords,
                                             const int* __restrict__ gcursor,
                                             const float* __restrict__ dinv,
                                             const float* __restrict__ bias,
                                             float* __restrict__ hout, int mode) {
    __shared__ float acc[NPB * 16];   // 8 KB
    __shared__ int ew[512];
    int tid = threadIdx.x;
    int b = blockIdx.x;

    for (int j = tid; j < NPB * 16; j += 512) acc[j] = 0.f;
    __syncthreads();

    int base = b * CAP;
    int count = gcursor[b] - base;
    int f = tid & 15;
    int g = tid >> 4;    // 0..31 edge groups

    for (int c = 0; c < count; c += 512) {
        int m = min(512, count - c);
        if (tid < m) ew[tid] = ewords[base + c + tid];
        __syncthreads();
        for (int i = g; i < m; i += 32) {
            int w = ew[i];
            int s = w & 0xFFFF;
            int ldst = (w >> 16) & 127;
            float v = hin[s * 16 + f];
            atomicAdd(&acc[(ldst << 4) + f], v);
        }
        __syncthreads();
    }

    // epilogue
    for (int j = tid; j < NPB * 16; j += 512) {
        int ldst = j >> 4;
        int ff = j & 15;
        int node = b * NPB + ldst;
        if (node < N_NODES) {
            float s = acc[j] + hin[node * 16 + ff];   // self loop (pre-scaled)
            float dv = dinv[node];
            float v;
            if (mode == 0) v = fmaxf(dv * s + bias[ff], 0.f) * dv;
            else           v = dv * s;
            hout[node * 16 + ff] = v;
        }
    }
}

// ---------------- GEMM 2: out[n][j] = b2[j] + sum_k s2[n][k] * W2[k][j] ----------

__global__ __launch_bounds__(256) void k_gemm2(const float* __restrict__ s2,
                                               const float* __restrict__ W2,
                                               const float* __restrict__ b2,
                                               float* __restrict__ out) {
    __shared__ float sw2[16 * 128];
    __shared__ float ss2[16 * 16];
    int tid = threadIdx.x;
    int n0 = blockIdx.x * 16;

    ((float4*)sw2)[tid] = ((const float4*)W2)[tid];
    ((float4*)sw2)[tid + 256] = ((const float4*)W2)[tid + 256];
    if (tid < 64) ((float4*)ss2)[tid] = ((const float4*)(s2 + (size_t)n0 * 16))[tid];
    __syncthreads();

    int j = tid & 127;
    int half = tid >> 7;
    float w[16];
#pragma unroll
    for (int k = 0; k < 16; k++) w[k] = sw2[k * 128 + j];
    float bj = b2[j];

#pragma unroll
    for (int r = 0; r < 8; r++) {
        int node = half + r * 2;
        float acc2 = bj;
#pragma unroll
        for (int k = 0; k < 16; k++) acc2 = fmaf(ss2[node * 16 + k], w[k], acc2);
        out[(size_t)(n0 + node) * 128 + j] = acc2;
    }
}

// ---------------- launch ----------------

extern "C" void kernel_launch(void* const* d_in, const int* in_sizes, int n_in,
                              void* d_out, int out_size, void* d_ws, size_t ws_size,
                              hipStream_t stream) {
    const float* x  = (const float*)d_in[0];
    const int*   ei = (const int*)d_in[1];
    const float* W1 = (const float*)d_in[2];
    const float* b1 = (const float*)d_in[3];
    const float* W2 = (const float*)d_in[4];
    const float* b2 = (const float*)d_in[5];
    float* out = (float*)d_out;

    const int E = in_sizes[1] / 2;            // 800000
    const int* src = ei;
    const int* dst = ei + E;

    // workspace layout (bytes)
    char* ws = (char*)d_ws;
    int*   gcursor = (int*)(ws + 0);                       // 2 KB (391 used)
    int*   ewords  = (int*)(ws + 2048);                    // 391*2816*4 = 4,404,224 B
    float* dinv    = (float*)(ws + 2048 + 4404224);        // 200,000 B
    float* h1s     = (float*)(ws + 2048 + 4404224 + 200000);          // 3.2 MB
    float* z1s     = (float*)(ws + 2048 + 4404224 + 200000 + 3200000); // 3.2 MB
    float* s2      = h1s;   // alias: h1s dead after agg1
    // total ~11.0 MB

    const int NCHUNK = (E + CHUNK - 1) / CHUNK;   // 196

    k_init<<<1, 512, 0, stream>>>(gcursor);
    k_part<<<NCHUNK, 512, 0, stream>>>(src, dst, gcursor, ewords, E);
    k_deg<<<NBUCKET, 256, 0, stream>>>(ewords, gcursor, dinv);
    k_gemm1<<<N_NODES / 16, 256, 0, stream>>>(x, W1, dinv, h1s);
    k_agg<<<NBUCKET, 512, 0, stream>>>(h1s, ewords, gcursor, dinv, b1, z1s, 0);
    k_agg<<<NBUCKET, 512, 0, stream>>>(z1s, ewords, gcursor, dinv, b2, s2, 1);
    k_gemm2<<<N_NODES / 16, 256, 0, stream>>>(s2, W2, b2, out);
}

// Round 3
// 157.290 us; speedup vs baseline: 1.8900x; 1.8900x over previous
//
#include <hip/hip_runtime.h>

#define N_NODES 50000
#define NPB 128                               // nodes per bucket
#define NBUCKET ((N_NODES + NPB - 1) / NPB)   // 391
#define CAP 2816                              // edges per bucket region (mean 2048 + 17 sigma)
#define CHUNK 4096                            // edges per partition block

// ---------------- init: per-bucket global cursors ----------------

__global__ void k_init(int* __restrict__ gcursor) {
    int b = threadIdx.x;
    if (b < NBUCKET) gcursor[b] = b * CAP;
}

// ---------------- partition: LDS counting-sort per chunk, coalesced run writes ----
// edge word: src(16b) | ldst(7b)<<16 | bucket(9b)<<23   (src < 50000 < 65536)

__global__ __launch_bounds__(512) void k_part(const int* __restrict__ src,
                                              const int* __restrict__ dst,
                                              int* __restrict__ gcursor,
                                              int* __restrict__ ewords, int E) {
    __shared__ int words[CHUNK];   // 16 KB
    __shared__ int hist[512];      // hist, then cursor
    __shared__ int lstart[512];
    __shared__ int gbase[512];

    int tid = threadIdx.x;
    int cbase = blockIdx.x * CHUNK;
    int count = min(CHUNK, E - cbase);

    hist[tid] = 0;
    __syncthreads();

    // phase 1: read edges, histogram buckets, keep packed words in regs
    int w[CHUNK / 512];
#pragma unroll
    for (int r = 0; r < CHUNK / 512; r++) {
        int i = cbase + tid + 512 * r;
        if (i < E) {
            int s = src[i];
            int d = dst[i];
            int b = d >> 7;
            w[r] = s | ((d & 127) << 16) | (b << 23);
            atomicAdd(&hist[b], 1);
        } else {
            w[r] = -1;
        }
    }
    __syncthreads();

    // phase 2: exclusive scan of hist[512]
    int h = hist[tid];
    for (int off = 1; off < 512; off <<= 1) {
        int t = (tid >= off) ? hist[tid - off] : 0;
        __syncthreads();
        hist[tid] += t;
        __syncthreads();
    }
    int excl = hist[tid] - h;
    __syncthreads();
    hist[tid] = excl;      // becomes local cursor
    lstart[tid] = excl;
    __syncthreads();

    // phase 3: scatter words into LDS grouped by bucket
#pragma unroll
    for (int r = 0; r < CHUNK / 512; r++) {
        if (w[r] != -1) {
            int b = ((unsigned)w[r]) >> 23;
            int pos = atomicAdd(&hist[b], 1);
            words[pos] = w[r];
        }
    }
    __syncthreads();

    // phase 4: one global cursor bump per bucket per chunk
    if (tid < NBUCKET) {
        int nb = hist[tid] - lstart[tid];
        gbase[tid] = (nb > 0) ? atomicAdd(&gcursor[tid], nb) : 0;
    }
    __syncthreads();

    // phase 5: coalesced run write-out
    for (int i = tid; i < count; i += 512) {
        int ww = words[i];
        int b = ((unsigned)ww) >> 23;
        int g = gbase[b] + (i - lstart[b]);   // absolute (gcursor init = b*CAP)
        ewords[g] = ww;
    }
}

// ---------------- per-bucket counting sort by local dst -> dst-sorted ushort CSR ----
// also emits row_start / deg / dinv per node

__global__ __launch_bounds__(256) void k_sort(const int* __restrict__ ewords,
                                              const int* __restrict__ gcursor,
                                              unsigned short* __restrict__ eidx,
                                              int* __restrict__ row_start,
                                              int* __restrict__ deg,
                                              float* __restrict__ dinv) {
    __shared__ unsigned short sorted[CAP];   // 5632 B
    __shared__ int hist[NPB];
    __shared__ int sc[NPB];
    int tid = threadIdx.x;
    int b = blockIdx.x;
    int base = b * CAP;
    int count = gcursor[b] - base;

    if (tid < NPB) hist[tid] = 0;
    __syncthreads();

    // load bucket edges into regs, histogram local dst
    int w[(CAP + 255) / 256];   // 11
#pragma unroll
    for (int r = 0; r < (CAP + 255) / 256; r++) {
        int i = tid + 256 * r;
        if (i < count) {
            int ww = ewords[base + i];
            w[r] = ww;
            atomicAdd(&hist[(ww >> 16) & 127], 1);
        } else {
            w[r] = -1;
        }
    }
    __syncthreads();

    // exclusive scan of hist[128] (Hillis-Steele, 128 active lanes)
    int v = 0;
    if (tid < NPB) { v = hist[tid]; sc[tid] = v; }
    __syncthreads();
    for (int off = 1; off < NPB; off <<= 1) {
        int t = 0;
        if (tid < NPB && tid >= off) t = sc[tid - off];
        __syncthreads();
        if (tid < NPB) sc[tid] += t;
        __syncthreads();
    }
    if (tid < NPB) {
        int excl = sc[tid] - v;
        int node = b * NPB + tid;
        if (node < N_NODES) {
            row_start[node] = base + excl;
            deg[node] = v;
            dinv[node] = rsqrtf((float)(v + 1));
        }
        hist[tid] = excl;   // becomes cursor
    }
    __syncthreads();

    // scatter into LDS sorted by local dst
#pragma unroll
    for (int r = 0; r < (CAP + 255) / 256; r++) {
        if (w[r] != -1) {
            int ldst = (w[r] >> 16) & 127;
            int pos = atomicAdd(&hist[ldst], 1);
            sorted[pos] = (unsigned short)(w[r] & 0xFFFF);
        }
    }
    __syncthreads();

    // coalesced write-out
    for (int i = tid; i < count; i += 256) eidx[base + i] = sorted[i];
}

// ---------------- GEMM 1: h1s[n][j] = dinv[n] * sum_k x[n][k] * W1[k][j] ----------

__global__ __launch_bounds__(256) void k_gemm1(const float* __restrict__ x,
                                               const float* __restrict__ W1,
                                               const float* __restrict__ dinv,
                                               float* __restrict__ h1s) {
    __shared__ float sx[16 * 132];
    __shared__ float swT[16 * 132];
    int tid = threadIdx.x;
    int n0 = blockIdx.x * 16;

#pragma unroll
    for (int r = 0; r < 2; r++) {
        int q = tid + 256 * r;
        float4 v = ((const float4*)W1)[q];
        int k = q >> 2;
        int j4 = (q & 3) << 2;
        swT[(j4 + 0) * 132 + k] = v.x;
        swT[(j4 + 1) * 132 + k] = v.y;
        swT[(j4 + 2) * 132 + k] = v.z;
        swT[(j4 + 3) * 132 + k] = v.w;
    }
    const float4* x4 = (const float4*)(x + (size_t)n0 * 128);
#pragma unroll
    for (int r = 0; r < 2; r++) {
        int q = tid + 256 * r;
        float4 v = x4[q];
        int node = q >> 5;
        int k = (q & 31) << 2;
        *(float4*)&sx[node * 132 + k] = v;
    }
    __syncthreads();

    int node = tid >> 4;
    int j = tid & 15;
    float acc = 0.f;
#pragma unroll
    for (int k = 0; k < 128; k += 4) {
        float4 a = *(const float4*)&sx[node * 132 + k];
        float4 bb = *(const float4*)&swT[j * 132 + k];
        acc = fmaf(a.x, bb.x, acc);
        acc = fmaf(a.y, bb.y, acc);
        acc = fmaf(a.z, bb.z, acc);
        acc = fmaf(a.w, bb.w, acc);
    }
    int n = n0 + node;
    h1s[(size_t)n * 16 + j] = dinv[n] * acc;
}

// ---------------- aggregation: one wave per node, gather from sorted CSR ----------
// lanes: f = lane&15 (feature), sub = lane>>4 (4-way edge parallel)
// mode 0: out = dinv * relu(dinv*(sum + self) + bias)   (hin pre-scaled by dinv[src])
// mode 1: out = dinv * (sum + self)

__global__ __launch_bounds__(256) void k_agg(const float* __restrict__ hin,
                                             const int* __restrict__ row_start,
                                             const int* __restrict__ deg,
                                             const unsigned short* __restrict__ eidx,
                                             const float* __restrict__ dinv,
                                             const float* __restrict__ bias,
                                             float* __restrict__ hout, int mode) {
    int lane = threadIdx.x & 63;
    int node = blockIdx.x * 4 + (threadIdx.x >> 6);   // grid = N/4 exactly
    int f = lane & 15;
    int sub = lane >> 4;

    int start = row_start[node];
    int d = deg[node];

    float a0 = 0.f, a1 = 0.f;
    int i = sub;
    for (; i + 4 < d; i += 8) {
        int s0 = eidx[start + i];
        int s1 = eidx[start + i + 4];
        a0 += hin[s0 * 16 + f];
        a1 += hin[s1 * 16 + f];
    }
    if (i < d) a0 += hin[(int)eidx[start + i] * 16 + f];
    float acc = a0 + a1;

    acc += __shfl_xor(acc, 16, 64);
    acc += __shfl_xor(acc, 32, 64);
    acc += hin[node * 16 + f];        // self loop (already dinv-scaled)

    float dv = dinv[node];
    float v;
    if (mode == 0) {
        v = fmaxf(dv * acc + bias[f], 0.f) * dv;
    } else {
        v = dv * acc;
    }
    if (sub == 0) hout[node * 16 + f] = v;
}

// ---------------- GEMM 2: out[n][j] = b2[j] + sum_k s2[n][k] * W2[k][j] ----------

__global__ __launch_bounds__(256) void k_gemm2(const float* __restrict__ s2,
                                               const float* __restrict__ W2,
                                               const float* __restrict__ b2,
                                               float* __restrict__ out) {
    __shared__ float sw2[16 * 128];
    __shared__ float ss2[16 * 16];
    int tid = threadIdx.x;
    int n0 = blockIdx.x * 16;

    ((float4*)sw2)[tid] = ((const float4*)W2)[tid];
    ((float4*)sw2)[tid + 256] = ((const float4*)W2)[tid + 256];
    if (tid < 64) ((float4*)ss2)[tid] = ((const float4*)(s2 + (size_t)n0 * 16))[tid];
    __syncthreads();

    int j = tid & 127;
    int half = tid >> 7;
    float w[16];
#pragma unroll
    for (int k = 0; k < 16; k++) w[k] = sw2[k * 128 + j];
    float bj = b2[j];

#pragma unroll
    for (int r = 0; r < 8; r++) {
        int node = half + r * 2;
        float acc2 = bj;
#pragma unroll
        for (int k = 0; k < 16; k++) acc2 = fmaf(ss2[node * 16 + k], w[k], acc2);
        out[(size_t)(n0 + node) * 128 + j] = acc2;
    }
}

// ---------------- launch ----------------

extern "C" void kernel_launch(void* const* d_in, const int* in_sizes, int n_in,
                              void* d_out, int out_size, void* d_ws, size_t ws_size,
                              hipStream_t stream) {
    const float* x  = (const float*)d_in[0];
    const int*   ei = (const int*)d_in[1];
    const float* W1 = (const float*)d_in[2];
    const float* b1 = (const float*)d_in[3];
    const float* W2 = (const float*)d_in[4];
    const float* b2 = (const float*)d_in[5];
    float* out = (float*)d_out;

    const int E = in_sizes[1] / 2;            // 800000
    const int* src = ei;
    const int* dst = ei + E;

    // workspace layout (bytes); ewords region is reused for h1s/s2 after k_sort
    char* ws = (char*)d_ws;
    int*            gcursor   = (int*)(ws + 0);             // 2 KB
    int*            ewords    = (int*)(ws + 2048);          // 391*2816*4 = 4,404,224
    float*          h1s       = (float*)(ws + 2048);        // alias: ewords dead after k_sort
    float*          s2        = h1s;                        // alias: h1s dead after agg1
    unsigned short* eidx      = (unsigned short*)(ws + 4406272);   // 391*2816*2 = 2,202,112
    int*            row_start = (int*)(ws + 6608384);       // 200,000
    int*            deg       = (int*)(ws + 6808384);       // 200,000
    float*          dinv      = (float*)(ws + 7008384);     // 200,000
    float*          z1s       = (float*)(ws + 7208384);     // 3,200,000
    // total ~10.41 MB

    const int NCHUNK = (E + CHUNK - 1) / CHUNK;   // 196

    k_init<<<1, 512, 0, stream>>>(gcursor);
    k_part<<<NCHUNK, 512, 0, stream>>>(src, dst, gcursor, ewords, E);
    k_sort<<<NBUCKET, 256, 0, stream>>>(ewords, gcursor, eidx, row_start, deg, dinv);
    k_gemm1<<<N_NODES / 16, 256, 0, stream>>>(x, W1, dinv, h1s);
    k_agg<<<N_NODES / 4, 256, 0, stream>>>(h1s, row_start, deg, eidx, dinv, b1, z1s, 0);
    k_agg<<<N_NODES / 4, 256, 0, stream>>>(z1s, row_start, deg, eidx, dinv, b2, s2, 1);
    k_gemm2<<<N_NODES / 16, 256, 0, stream>>>(s2, W2, b2, out);
}